// Round 3
// baseline (692.608 us; speedup 1.0000x reference)
//
#include <hip/hip_runtime.h>

#define D 128
#define NN 512
#define BB 512

typedef __attribute__((ext_vector_type(8))) short short8;
typedef __attribute__((ext_vector_type(4))) float f32x4;

__device__ __forceinline__ unsigned int fbits(float f) {
  union { float f; unsigned int u; } v; v.f = f; return v.u;
}
__device__ __forceinline__ float ubits(unsigned int u) {
  union { unsigned int u; float f; } v; v.u = u; return v.f;
}
__device__ __forceinline__ float bf2f(unsigned short u) { return ubits(((unsigned int)u) << 16); }
__device__ __forceinline__ unsigned short f2bf(float f) {
  unsigned int x = fbits(f);
  return (unsigned short)((x + 0x7fffu + ((x >> 16) & 1u)) >> 16);
}
__device__ __forceinline__ float lrelu(float x) { return x > 0.f ? x : 0.01f * x; }

// ---- prep: Wkk = Wk @ Wa1 (fp32 -> split bf16 Wh/Wl), c3 = rel @ Wa3 + b_att (fp32)
__global__ __launch_bounds__(128) void prep_kernel(
    const float* __restrict__ Wk, const float* __restrict__ Watt,
    const float* __restrict__ batt, const float* __restrict__ rel,
    unsigned short* __restrict__ Wh, unsigned short* __restrict__ Wl,
    float* __restrict__ c3) {
  const int blk = blockIdx.x, d = threadIdx.x;
  if (blk < D) {
    float a0 = 0.f, a1 = 0.f, a2 = 0.f, a3 = 0.f;
    for (int j = 0; j < D; j += 4) {
      a0 += Wk[blk * D + j + 0] * Watt[(j + 0) * D + d];
      a1 += Wk[blk * D + j + 1] * Watt[(j + 1) * D + d];
      a2 += Wk[blk * D + j + 2] * Watt[(j + 2) * D + d];
      a3 += Wk[blk * D + j + 3] * Watt[(j + 3) * D + d];
    }
    const float w = (a0 + a1) + (a2 + a3);
    const unsigned int ub = fbits(w);
    Wh[blk * D + d] = (unsigned short)(ub >> 16);                 // truncated high bf16
    Wl[blk * D + d] = f2bf(w - ubits(ub & 0xFFFF0000u));          // residual bf16
  } else {
    const int b = blk - D;
    float a0 = batt[d], a1 = 0.f, a2 = 0.f, a3 = 0.f;
    for (int j = 0; j < D; j += 4) {
      a0 += rel[b * D + j + 0] * Watt[(2 * D + j + 0) * D + d];
      a1 += rel[b * D + j + 1] * Watt[(2 * D + j + 1) * D + d];
      a2 += rel[b * D + j + 2] * Watt[(2 * D + j + 2) * D + d];
      a3 += rel[b * D + j + 3] * Watt[(2 * D + j + 3) * D + d];
    }
    c3[b * D + d] = (a0 + a1) + (a2 + a3);
  }
}

// ---- g1 = (key*mask) @ Wkk via split-bf16 MFMA: ah*Wh + al*Wh + ah*Wl (fp32-accurate)
template <int F32OUT>
__global__ __launch_bounds__(256) void gemm_g1_kernel(
    const float* __restrict__ key, const int* __restrict__ mask,
    const unsigned short* __restrict__ Wh, const unsigned short* __restrict__ Wl,
    void* __restrict__ g1out) {
  __shared__ __align__(16) unsigned short whlds[16384];
  __shared__ __align__(16) unsigned short wllds[16384];
  const int t = threadIdx.x;
  // coalesced load + scatter into MFMA-fragment order:
  // chunk((c*4+kt)*64+lane)[j] = W[k=kt*32+(lane>>4)*8+j][n=c*16+(lane&15)]
  for (int i = 0; i < 8; ++i) {
    const int unit = t + i * 256;            // 0..2047
    const int k = unit >> 4, n0 = (unit & 15) * 8;
    const uint4 hv = *reinterpret_cast<const uint4*>(Wh + k * D + n0);
    const uint4 lv = *reinterpret_cast<const uint4*>(Wl + k * D + n0);
    const unsigned short* hp = reinterpret_cast<const unsigned short*>(&hv);
    const unsigned short* lp = reinterpret_cast<const unsigned short*>(&lv);
    const int kt = k >> 5, q = (k >> 3) & 3, j = k & 7;
    #pragma unroll
    for (int j2 = 0; j2 < 8; ++j2) {
      const int n = n0 + j2;
      const int idx = (((n >> 4) * 4 + kt) * 64 + q * 16 + (n & 15)) * 8 + j;
      whlds[idx] = hp[j2];
      wllds[idx] = lp[j2];
    }
  }
  __syncthreads();
  const int wave = t >> 6, lane = t & 63;
  const int q = lane >> 4, l15 = lane & 15;
  const int ntiles = (BB * NN) / 64;
  for (int tile = blockIdx.x; tile < ntiles; tile += gridDim.x) {
    const long rowbase = (long)tile * 64 + wave * 16;
    const long r = rowbase + l15;
    const int mk = mask[r];
    f32x4 acc[8];
    #pragma unroll
    for (int c = 0; c < 8; ++c) acc[c] = (f32x4){0.f, 0.f, 0.f, 0.f};
    #pragma unroll
    for (int kt = 0; kt < 4; ++kt) {
      const float* kp = key + r * D + kt * 32 + q * 8;
      float xs[8];
      *reinterpret_cast<float4*>(&xs[0]) = *reinterpret_cast<const float4*>(kp);
      *reinterpret_cast<float4*>(&xs[4]) = *reinterpret_cast<const float4*>(kp + 4);
      union { unsigned int u[4]; short8 v; } cvh, cvl;
      #pragma unroll
      for (int p2 = 0; p2 < 4; ++p2) {
        float a = xs[2 * p2], b = xs[2 * p2 + 1];
        if (!mk) { a = 0.f; b = 0.f; }
        const unsigned int ua = fbits(a), ub = fbits(b);
        cvh.u[p2] = (ua >> 16) | (ub & 0xFFFF0000u);
        const float ra = a - ubits(ua & 0xFFFF0000u);
        const float rb = b - ubits(ub & 0xFFFF0000u);
        cvl.u[p2] = (unsigned int)f2bf(ra) | ((unsigned int)f2bf(rb) << 16);
      }
      const short8 ah = cvh.v, al = cvl.v;
      #pragma unroll
      for (int c = 0; c < 8; ++c) {
        const short8 bh = *reinterpret_cast<const short8*>(&whlds[((c * 4 + kt) * 64 + lane) * 8]);
        const short8 bl = *reinterpret_cast<const short8*>(&wllds[((c * 4 + kt) * 64 + lane) * 8]);
        acc[c] = __builtin_amdgcn_mfma_f32_16x16x32_bf16(ah, bh, acc[c], 0, 0, 0);
        acc[c] = __builtin_amdgcn_mfma_f32_16x16x32_bf16(al, bh, acc[c], 0, 0, 0);
        acc[c] = __builtin_amdgcn_mfma_f32_16x16x32_bf16(ah, bl, acc[c], 0, 0, 0);
      }
    }
    // C/D layout (m89): col = c*16 + (lane&15), row = rowbase + (lane>>4)*4 + reg
    #pragma unroll
    for (int c = 0; c < 8; ++c) {
      #pragma unroll
      for (int reg = 0; reg < 4; ++reg) {
        const long row = rowbase + q * 4 + reg;
        const int col = c * 16 + l15;
        if (F32OUT) ((float*)g1out)[row * D + col] = acc[c][reg];
        else        ((unsigned short*)g1out)[row * D + col] = f2bf(acc[c][reg]);
      }
    }
  }
}

// ---- fused 3-hop kernel: one block per batch row b -----------------------------
template <int G1F32>
__global__ __launch_bounds__(256) void hops_kernel(
    const float* __restrict__ e1, const int* __restrict__ mask,
    const float* __restrict__ value, const void* __restrict__ g1void,
    const float* __restrict__ Wlin, const float* __restrict__ blin,
    const float* __restrict__ Watt, const float* __restrict__ Wv,
    const float* __restrict__ c3, float* __restrict__ out) {
  __shared__ float uS[D], cS[D], ubS[D], opS[D];
  __shared__ float attS[NN];
  __shared__ float oscr[4][D];
  __shared__ float redA[4], redB[4];
  const int b = blockIdx.x;
  const int t = threadIdx.x;
  const int wv = t >> 6, lane = t & 63;
  const long base = (long)b * NN * D;
  const float* g1f = (const float*)g1void;
  const unsigned short* g1h = (const unsigned short*)g1void;
  const float* vb = value + base;
  const int* mb = mask + b * NN;
  if (t < D) uS[t] = e1[b * D + t];
  __syncthreads();
  for (int hop = 0; hop < 3; ++hop) {
    // phase 1: c = u@Wa2 + c3 (t<128); ub = lrelu(u@Wlin + blin) (t>=128)
    {
      const int d = t & 127;
      const float* W = (t < D) ? (Watt + D * D) : Wlin;
      float a0 = 0.f, a1 = 0.f, a2 = 0.f, a3 = 0.f;
      for (int k = 0; k < D; k += 4) {
        a0 += uS[k + 0] * W[(k + 0) * D + d];
        a1 += uS[k + 1] * W[(k + 1) * D + d];
        a2 += uS[k + 2] * W[(k + 2) * D + d];
        a3 += uS[k + 3] * W[(k + 3) * D + d];
      }
      const float acc = (a0 + a1) + (a2 + a3);
      if (t < D) cS[d] = acc + c3[b * D + d];
      else       ubS[d] = lrelu(acc + blin[d]);
    }
    __syncthreads();
    // phase 2: att[n] = sum_d lrelu(g1[n,d] + c[d]); 16 lanes per row
    {
      const int grp = t >> 4, l = t & 15, d0 = l * 8;
      float creg[8];
      #pragma unroll
      for (int j = 0; j < 8; ++j) creg[j] = cS[d0 + j];
      for (int i = 0; i < 32; ++i) {
        const int n = i * 16 + grp;
        float vals[8];
        if (G1F32) {
          *reinterpret_cast<float4*>(&vals[0]) = *reinterpret_cast<const float4*>(g1f + base + (long)n * D + d0);
          *reinterpret_cast<float4*>(&vals[4]) = *reinterpret_cast<const float4*>(g1f + base + (long)n * D + d0 + 4);
        } else {
          const uint4 raw = *reinterpret_cast<const uint4*>(g1h + base + (long)n * D + d0);
          const unsigned short* e = reinterpret_cast<const unsigned short*>(&raw);
          #pragma unroll
          for (int j = 0; j < 8; ++j) vals[j] = bf2f(e[j]);
        }
        float s = 0.f;
        #pragma unroll
        for (int j = 0; j < 8; ++j) s += lrelu(vals[j] + creg[j]);
        #pragma unroll
        for (int off = 8; off > 0; off >>= 1) s += __shfl_xor(s, off, 16);
        if (l == 0) attS[n] = s;
      }
    }
    __syncthreads();
    // phase 3: masked softmax over n (max over ALL n incl. masked — matches ref)
    {
      float m = fmaxf(attS[t], attS[t + 256]);
      #pragma unroll
      for (int off = 32; off > 0; off >>= 1) m = fmaxf(m, __shfl_xor(m, off, 64));
      if (lane == 0) redA[wv] = m;
      __syncthreads();
      m = fmaxf(fmaxf(redA[0], redA[1]), fmaxf(redA[2], redA[3]));
      const float e0  = __expf(attS[t] - m)       * (mb[t] ? 1.f : 0.f);
      const float e1v = __expf(attS[t + 256] - m) * (mb[t + 256] ? 1.f : 0.f);
      float ss = e0 + e1v;
      #pragma unroll
      for (int off = 32; off > 0; off >>= 1) ss += __shfl_xor(ss, off, 64);
      if (lane == 0) redB[wv] = ss;
      __syncthreads();
      const float s = redB[0] + redB[1] + redB[2] + redB[3] + 1e-5f;
      attS[t] = e0 / s;
      attS[t + 256] = e1v / s;
    }
    __syncthreads();
    // phase 4: o_pre[d] = sum_n p[n] * value[n,d]
    {
      const int grp = t >> 4, l = t & 15, d0 = l * 8;
      float acc8[8];
      #pragma unroll
      for (int j = 0; j < 8; ++j) acc8[j] = 0.f;
      for (int i = 0; i < 32; ++i) {
        const int n = i * 16 + grp;
        const float p = attS[n];
        float vv[8];
        *reinterpret_cast<float4*>(&vv[0]) = *reinterpret_cast<const float4*>(vb + (long)n * D + d0);
        *reinterpret_cast<float4*>(&vv[4]) = *reinterpret_cast<const float4*>(vb + (long)n * D + d0 + 4);
        #pragma unroll
        for (int j = 0; j < 8; ++j) acc8[j] += p * vv[j];
      }
      #pragma unroll
      for (int j = 0; j < 8; ++j) {
        acc8[j] += __shfl_xor(acc8[j], 16, 64);
        acc8[j] += __shfl_xor(acc8[j], 32, 64);
      }
      if (lane < 16) {
        #pragma unroll
        for (int j = 0; j < 8; ++j) oscr[wv][lane * 8 + j] = acc8[j];
      }
    }
    __syncthreads();
    if (t < D) opS[t] = oscr[0][t] + oscr[1][t] + oscr[2][t] + oscr[3][t];
    __syncthreads();
    // phase 5: o = o_pre @ Wv ; u = l2norm(ub + o)
    {
      float un = 0.f, sq = 0.f;
      if (t < D) {
        float a0 = 0.f, a1 = 0.f, a2 = 0.f, a3 = 0.f;
        for (int k = 0; k < D; k += 4) {
          a0 += opS[k + 0] * Wv[(k + 0) * D + t];
          a1 += opS[k + 1] * Wv[(k + 1) * D + t];
          a2 += opS[k + 2] * Wv[(k + 2) * D + t];
          a3 += opS[k + 3] * Wv[(k + 3) * D + t];
        }
        un = ubS[t] + ((a0 + a1) + (a2 + a3));
        sq = un * un;
      }
      #pragma unroll
      for (int off = 32; off > 0; off >>= 1) sq += __shfl_xor(sq, off, 64);
      if (lane == 0) redA[wv] = sq;
      __syncthreads();
      const float ns = redA[0] + redA[1] + redA[2] + redA[3];
      const float norm = sqrtf(ns);
      const float inv = (norm > 1e-12f) ? (1.f / norm) : 1e12f;
      if (t < D) uS[t] = un * inv;
    }
    __syncthreads();
  }
  if (t < D) out[b * D + t] = uS[t];   // fp32 output
}

extern "C" void kernel_launch(void* const* d_in, const int* in_sizes, int n_in,
                              void* d_out, int out_size, void* d_ws, size_t ws_size,
                              hipStream_t stream) {
  const float* e1   = (const float*)d_in[0];
  const float* rel  = (const float*)d_in[1];
  const float* key  = (const float*)d_in[2];
  const float* val  = (const float*)d_in[3];
  const int*   mask = (const int*)d_in[4];
  const float* Wk   = (const float*)d_in[5];
  const float* Wv   = (const float*)d_in[6];
  const float* Wlin = (const float*)d_in[7];
  const float* blin = (const float*)d_in[8];
  const float* Watt = (const float*)d_in[9];
  const float* batt = (const float*)d_in[10];
  float* out = (float*)d_out;

  char* ws = (char*)d_ws;
  unsigned short* Wh = (unsigned short*)ws;                  // 32 KB
  unsigned short* Wl = (unsigned short*)(ws + 32 * 1024);    // 32 KB
  float*          c3 = (float*)(ws + 64 * 1024);             // 256 KB
  void*           g1 = (void*)(ws + 512 * 1024);             // 134 MB fp32 (or 67 MB bf16)

  const size_t need_f32 = 512 * 1024 + (size_t)BB * NN * D * sizeof(float);
  const bool f32g1 = (ws_size >= need_f32);

  prep_kernel<<<D + BB, 128, 0, stream>>>(Wk, Watt, batt, rel, Wh, Wl, c3);
  if (f32g1) {
    gemm_g1_kernel<1><<<2048, 256, 0, stream>>>(key, mask, Wh, Wl, g1);
    hops_kernel<1><<<BB, 256, 0, stream>>>(e1, mask, val, g1, Wlin, blin, Watt, Wv, c3, out);
  } else {
    gemm_g1_kernel<0><<<2048, 256, 0, stream>>>(key, mask, Wh, Wl, g1);
    hops_kernel<0><<<BB, 256, 0, stream>>>(e1, mask, val, g1, Wlin, blin, Watt, Wv, c3, out);
  }
}

// Round 4
// 508.860 us; speedup vs baseline: 1.3611x; 1.3611x over previous
//
#include <hip/hip_runtime.h>

#define D 128
#define NN 512
#define BB 512

typedef __attribute__((ext_vector_type(8))) short short8;
typedef __attribute__((ext_vector_type(4))) float f32x4;

__device__ __forceinline__ unsigned int fbits(float f) {
  union { float f; unsigned int u; } v; v.f = f; return v.u;
}
__device__ __forceinline__ float ubits(unsigned int u) {
  union { unsigned int u; float f; } v; v.u = u; return v.f;
}
__device__ __forceinline__ unsigned short f2bf(float f) {
  unsigned int x = fbits(f);
  return (unsigned short)((x + 0x7fffu + ((x >> 16) & 1u)) >> 16);
}
__device__ __forceinline__ float h2f(unsigned short u) {
  _Float16 h; __builtin_memcpy(&h, &u, 2); return (float)h;
}
__device__ __forceinline__ unsigned short f2h(float f) {
  _Float16 h = (_Float16)f; unsigned short u; __builtin_memcpy(&u, &h, 2); return u;
}
__device__ __forceinline__ float lrelu(float x) { return x > 0.f ? x : 0.01f * x; }

// ---- prep: Wh/Wl = split-bf16(Wk @ Wa1); c3 = rel @ Wa3 + b_att (fp32) --------
__global__ __launch_bounds__(256) void prep_kernel(
    const float* __restrict__ Wk, const float* __restrict__ Watt,
    const float* __restrict__ batt, const float* __restrict__ rel,
    unsigned short* __restrict__ Wh, unsigned short* __restrict__ Wl,
    float* __restrict__ c3) {
  __shared__ float rowS[D];
  __shared__ float psum[2][D];
  const int blk = blockIdx.x;      // 0..(D+BB-1)
  const int t = threadIdx.x;       // 256
  const float* src = (blk < D) ? (Wk + blk * D) : (rel + (blk - D) * D);
  const float* W   = (blk < D) ? Watt : (Watt + 2 * D * D);
  if (t < D) rowS[t] = src[t];
  __syncthreads();
  const int d = t & 127, half = t >> 7;
  const float* Wp = W + (half * 64) * D + d;
  float a = 0.f;
  #pragma unroll 8
  for (int k = 0; k < 64; ++k) a += rowS[half * 64 + k] * Wp[k * D];
  psum[half][d] = a;
  __syncthreads();
  if (t < D) {
    const float w = psum[0][t] + psum[1][t];
    if (blk < D) {
      const unsigned int ub = fbits(w);
      Wh[blk * D + t] = (unsigned short)(ub >> 16);
      Wl[blk * D + t] = f2bf(w - ubits(ub & 0xFFFF0000u));
    } else {
      c3[(blk - D) * D + t] = w + batt[t];
    }
  }
}

// ---- g1 = (key*mask) @ Wkk via split-bf16 MFMA (fp32-accurate), stored fp16 ----
__global__ __launch_bounds__(256) void gemm_g1_kernel(
    const float* __restrict__ key, const int* __restrict__ mask,
    const unsigned short* __restrict__ Wh, const unsigned short* __restrict__ Wl,
    unsigned short* __restrict__ g1h) {
  __shared__ __align__(16) unsigned short whlds[16384];
  __shared__ __align__(16) unsigned short wllds[16384];
  const int t = threadIdx.x;
  // coalesced load + scatter into MFMA-fragment order:
  // chunk((c*4+kt)*64+lane)[j] = W[k=kt*32+(lane>>4)*8+j][n=c*16+(lane&15)]
  for (int i = 0; i < 8; ++i) {
    const int unit = t + i * 256;            // 0..2047
    const int k = unit >> 4, n0 = (unit & 15) * 8;
    const uint4 hv = *reinterpret_cast<const uint4*>(Wh + k * D + n0);
    const uint4 lv = *reinterpret_cast<const uint4*>(Wl + k * D + n0);
    const unsigned short* hp = reinterpret_cast<const unsigned short*>(&hv);
    const unsigned short* lp = reinterpret_cast<const unsigned short*>(&lv);
    const int kt = k >> 5, q = (k >> 3) & 3, j = k & 7;
    #pragma unroll
    for (int j2 = 0; j2 < 8; ++j2) {
      const int n = n0 + j2;
      const int idx = (((n >> 4) * 4 + kt) * 64 + q * 16 + (n & 15)) * 8 + j;
      whlds[idx] = hp[j2];
      wllds[idx] = lp[j2];
    }
  }
  __syncthreads();
  const int wave = t >> 6, lane = t & 63;
  const int q = lane >> 4, l15 = lane & 15;
  const int ntiles = (BB * NN) / 64;
  for (int tile = blockIdx.x; tile < ntiles; tile += gridDim.x) {
    const long rowbase = (long)tile * 64 + wave * 16;
    const long r = rowbase + l15;
    const int mk = mask[r];
    short8 ah[4], al[4];
    #pragma unroll
    for (int kt = 0; kt < 4; ++kt) {
      const float* kp = key + r * D + kt * 32 + q * 8;
      float xs[8];
      *reinterpret_cast<float4*>(&xs[0]) = *reinterpret_cast<const float4*>(kp);
      *reinterpret_cast<float4*>(&xs[4]) = *reinterpret_cast<const float4*>(kp + 4);
      union { unsigned int u[4]; short8 v; } cvh, cvl;
      #pragma unroll
      for (int p2 = 0; p2 < 4; ++p2) {
        float a = xs[2 * p2], b = xs[2 * p2 + 1];
        if (!mk) { a = 0.f; b = 0.f; }
        const unsigned int ua = fbits(a), ub = fbits(b);
        cvh.u[p2] = (ua >> 16) | (ub & 0xFFFF0000u);
        const float ra = a - ubits(ua & 0xFFFF0000u);
        const float rb = b - ubits(ub & 0xFFFF0000u);
        cvl.u[p2] = (unsigned int)f2bf(ra) | ((unsigned int)f2bf(rb) << 16);
      }
      ah[kt] = cvh.v; al[kt] = cvl.v;
    }
    f32x4 acc[8];
    #pragma unroll
    for (int c = 0; c < 8; ++c) acc[c] = (f32x4){0.f, 0.f, 0.f, 0.f};
    #pragma unroll
    for (int kt = 0; kt < 4; ++kt) {
      #pragma unroll
      for (int c = 0; c < 8; ++c) {
        const short8 bh = *reinterpret_cast<const short8*>(&whlds[((c * 4 + kt) * 64 + lane) * 8]);
        const short8 bl = *reinterpret_cast<const short8*>(&wllds[((c * 4 + kt) * 64 + lane) * 8]);
        acc[c] = __builtin_amdgcn_mfma_f32_16x16x32_bf16(ah[kt], bh, acc[c], 0, 0, 0);
        acc[c] = __builtin_amdgcn_mfma_f32_16x16x32_bf16(al[kt], bh, acc[c], 0, 0, 0);
        acc[c] = __builtin_amdgcn_mfma_f32_16x16x32_bf16(ah[kt], bl, acc[c], 0, 0, 0);
      }
    }
    // C/D layout: col(n) = c*16 + (lane&15), row(m) = rowbase + (lane>>4)*4 + reg
    #pragma unroll
    for (int c = 0; c < 8; ++c) {
      #pragma unroll
      for (int reg = 0; reg < 4; ++reg) {
        const long row = rowbase + q * 4 + reg;
        g1h[row * D + c * 16 + l15] = f2h(acc[c][reg]);
      }
    }
  }
}

// ---- fused 3-hop kernel: one block (512 thr) per batch row ---------------------
template <int USEVH>
__global__ __launch_bounds__(512, 4) void hops_kernel(
    const float* __restrict__ e1, const int* __restrict__ mask,
    const float* __restrict__ value, const unsigned short* __restrict__ g1h,
    unsigned short* __restrict__ vh,
    const float* __restrict__ Wlin, const float* __restrict__ blin,
    const float* __restrict__ Watt, const float* __restrict__ Wv,
    const float* __restrict__ c3, float* __restrict__ out) {
  __shared__ float uS[D], cS[D], ubS[D], opS[D];
  __shared__ float attS[NN];
  __shared__ float part[4][D];
  __shared__ float oscr[8][D];
  __shared__ float redA[8], redB[8];
  const int b = blockIdx.x;
  const int t = threadIdx.x;
  const int wv = t >> 6, lane = t & 63;
  const long base = (long)b * NN * D;
  const int* mb = mask + b * NN;
  if (t < D) uS[t] = e1[b * D + t];
  __syncthreads();
  for (int hop = 0; hop < 3; ++hop) {
    // phase 1: 4 roles x 128 threads: role0/1 = c halves, role2/3 = ub halves
    {
      const int d = t & 127, role = t >> 7;
      const float* W = (role < 2) ? (Watt + D * D) : Wlin;
      const int k0 = (role & 1) * 64;
      const float* Wp = W + k0 * D + d;
      float a = 0.f;
      #pragma unroll 8
      for (int k = 0; k < 64; ++k) a += uS[k0 + k] * Wp[k * D];
      part[role][d] = a;
    }
    __syncthreads();
    if (t < D) cS[t] = part[0][t] + part[1][t] + c3[b * D + t];
    else if (t < 2 * D) { const int d = t - D; ubS[d] = lrelu(part[2][d] + part[3][d] + blin[d]); }
    __syncthreads();
    // phase 2: att[n] = sum_d lrelu(g1[n,d] + c[d]); 32 groups x 16 lanes, 16 iters
    {
      const int grp = t >> 4, l = t & 15, d0 = l * 8;
      float creg[8];
      #pragma unroll
      for (int j = 0; j < 8; ++j) creg[j] = cS[d0 + j];
      #pragma unroll 4
      for (int i = 0; i < 16; ++i) {
        const int n = i * 32 + grp;
        const uint4 raw = *reinterpret_cast<const uint4*>(g1h + base + (long)n * D + d0);
        const unsigned short* e = reinterpret_cast<const unsigned short*>(&raw);
        float s = 0.f;
        #pragma unroll
        for (int j = 0; j < 8; ++j) s += lrelu(h2f(e[j]) + creg[j]);
        #pragma unroll
        for (int off = 8; off > 0; off >>= 1) s += __shfl_xor(s, off, 16);
        if (l == 0) attS[n] = s;
      }
    }
    __syncthreads();
    // phase 3: masked softmax (max over ALL n incl. masked — matches ref); n = t
    {
      const float av = attS[t];
      float m = av;
      #pragma unroll
      for (int off = 32; off > 0; off >>= 1) m = fmaxf(m, __shfl_xor(m, off, 64));
      if (lane == 0) redA[wv] = m;
      __syncthreads();
      m = redA[0];
      #pragma unroll
      for (int w2 = 1; w2 < 8; ++w2) m = fmaxf(m, redA[w2]);
      const float e0 = __expf(av - m) * (mb[t] ? 1.f : 0.f);
      float ss = e0;
      #pragma unroll
      for (int off = 32; off > 0; off >>= 1) ss += __shfl_xor(ss, off, 64);
      if (lane == 0) redB[wv] = ss;
      __syncthreads();
      float s = 1e-5f;
      #pragma unroll
      for (int w2 = 0; w2 < 8; ++w2) s += redB[w2];
      attS[t] = e0 / s;
    }
    __syncthreads();
    // phase 4: o_pre[d] = sum_n p[n] * value[n,d]; hop0 converts value -> fp16 ws
    {
      const int grp = t >> 4, l = t & 15, d0 = l * 8;
      float acc8[8];
      #pragma unroll
      for (int j = 0; j < 8; ++j) acc8[j] = 0.f;
      if (USEVH && hop == 0) {
        #pragma unroll 2
        for (int i = 0; i < 16; ++i) {
          const int n = i * 32 + grp;
          const float p = attS[n];
          float vv[8];
          *reinterpret_cast<float4*>(&vv[0]) = *reinterpret_cast<const float4*>(value + base + (long)n * D + d0);
          *reinterpret_cast<float4*>(&vv[4]) = *reinterpret_cast<const float4*>(value + base + (long)n * D + d0 + 4);
          unsigned short hv[8];
          #pragma unroll
          for (int j = 0; j < 8; ++j) { hv[j] = f2h(vv[j]); acc8[j] += p * vv[j]; }
          *reinterpret_cast<uint4*>(vh + base + (long)n * D + d0) = *reinterpret_cast<const uint4*>(hv);
        }
      } else if (USEVH) {
        #pragma unroll 4
        for (int i = 0; i < 16; ++i) {
          const int n = i * 32 + grp;
          const float p = attS[n];
          const uint4 raw = *reinterpret_cast<const uint4*>(vh + base + (long)n * D + d0);
          const unsigned short* e = reinterpret_cast<const unsigned short*>(&raw);
          #pragma unroll
          for (int j = 0; j < 8; ++j) acc8[j] += p * h2f(e[j]);
        }
      } else {
        #pragma unroll 2
        for (int i = 0; i < 16; ++i) {
          const int n = i * 32 + grp;
          const float p = attS[n];
          float vv[8];
          *reinterpret_cast<float4*>(&vv[0]) = *reinterpret_cast<const float4*>(value + base + (long)n * D + d0);
          *reinterpret_cast<float4*>(&vv[4]) = *reinterpret_cast<const float4*>(value + base + (long)n * D + d0 + 4);
          #pragma unroll
          for (int j = 0; j < 8; ++j) acc8[j] += p * vv[j];
        }
      }
      #pragma unroll
      for (int j = 0; j < 8; ++j) {
        acc8[j] += __shfl_xor(acc8[j], 16, 64);
        acc8[j] += __shfl_xor(acc8[j], 32, 64);
      }
      if (lane < 16) {
        #pragma unroll
        for (int j = 0; j < 8; ++j) oscr[wv][lane * 8 + j] = acc8[j];
      }
    }
    __syncthreads();
    if (t < D) {
      float s = 0.f;
      #pragma unroll
      for (int w2 = 0; w2 < 8; ++w2) s += oscr[w2][t];
      opS[t] = s;
    }
    __syncthreads();
    // phase 5a: o = o_pre @ Wv, 4-way k-split
    {
      const int d = t & 127, role = t >> 7;
      const int k0 = role * 32;
      const float* Wp = Wv + k0 * D + d;
      float a = 0.f;
      #pragma unroll 8
      for (int k = 0; k < 32; ++k) a += opS[k0 + k] * Wp[k * D];
      part[role][d] = a;
    }
    __syncthreads();
    // phase 5b: u = l2norm(ub + o)
    {
      float un = 0.f, sq = 0.f;
      if (t < D) {
        un = ubS[t] + part[0][t] + part[1][t] + part[2][t] + part[3][t];
        sq = un * un;
      }
      #pragma unroll
      for (int off = 32; off > 0; off >>= 1) sq += __shfl_xor(sq, off, 64);
      if (lane == 0) redA[wv] = sq;
      __syncthreads();
      float ns = 0.f;
      #pragma unroll
      for (int w2 = 0; w2 < 8; ++w2) ns += redA[w2];
      const float norm = sqrtf(ns);
      const float inv = (norm > 1e-12f) ? (1.f / norm) : 1e12f;
      if (t < D) uS[t] = un * inv;
    }
    __syncthreads();
  }
  if (t < D) out[b * D + t] = uS[t];
}

extern "C" void kernel_launch(void* const* d_in, const int* in_sizes, int n_in,
                              void* d_out, int out_size, void* d_ws, size_t ws_size,
                              hipStream_t stream) {
  const float* e1   = (const float*)d_in[0];
  const float* rel  = (const float*)d_in[1];
  const float* key  = (const float*)d_in[2];
  const float* val  = (const float*)d_in[3];
  const int*   mask = (const int*)d_in[4];
  const float* Wk   = (const float*)d_in[5];
  const float* Wv   = (const float*)d_in[6];
  const float* Wlin = (const float*)d_in[7];
  const float* blin = (const float*)d_in[8];
  const float* Watt = (const float*)d_in[9];
  const float* batt = (const float*)d_in[10];
  float* out = (float*)d_out;

  char* ws = (char*)d_ws;
  unsigned short* Wh  = (unsigned short*)ws;                   // 32 KB
  unsigned short* Wl  = (unsigned short*)(ws + 32 * 1024);     // 32 KB
  float*          c3  = (float*)(ws + 64 * 1024);              // 256 KB
  unsigned short* g1h = (unsigned short*)(ws + 512 * 1024);    // 64 MiB fp16
  const size_t g1bytes = (size_t)BB * NN * D * sizeof(unsigned short);
  unsigned short* vh  = (unsigned short*)(ws + 512 * 1024 + g1bytes);  // 64 MiB fp16

  const size_t need_vh = 512 * 1024 + 2 * g1bytes;
  const bool usevh = (ws_size >= need_vh);

  prep_kernel<<<D + BB, 256, 0, stream>>>(Wk, Watt, batt, rel, Wh, Wl, c3);
  gemm_g1_kernel<<<4096, 256, 0, stream>>>(key, mask, Wh, Wl, g1h);
  if (usevh) {
    hops_kernel<1><<<BB, 512, 0, stream>>>(e1, mask, val, g1h, vh, Wlin, blin, Watt, Wv, c3, out);
  } else {
    hops_kernel<0><<<BB, 512, 0, stream>>>(e1, mask, val, g1h, vh, Wlin, blin, Watt, Wv, c3, out);
  }
}

// Round 5
// 396.461 us; speedup vs baseline: 1.7470x; 1.2835x over previous
//
#include <hip/hip_runtime.h>

#define D 128
#define NN 512
#define BB 512

typedef __attribute__((ext_vector_type(8))) short short8;
typedef __attribute__((ext_vector_type(4))) float f32x4;

__device__ __forceinline__ unsigned int fbits(float f) {
  union { float f; unsigned int u; } v; v.f = f; return v.u;
}
__device__ __forceinline__ float ubits(unsigned int u) {
  union { unsigned int u; float f; } v; v.u = u; return v.f;
}
__device__ __forceinline__ unsigned short f2bf(float f) {
  unsigned int x = fbits(f);
  return (unsigned short)((x + 0x7fffu + ((x >> 16) & 1u)) >> 16);
}
__device__ __forceinline__ float h2f(unsigned short u) {
  _Float16 h; __builtin_memcpy(&h, &u, 2); return (float)h;
}
__device__ __forceinline__ unsigned short f2h(float f) {
  _Float16 h = (_Float16)f; unsigned short u; __builtin_memcpy(&u, &h, 2); return u;
}
__device__ __forceinline__ float lrelu(float x) { return x > 0.f ? x : 0.01f * x; }

// MFMA fragment-order index for W[k][n] (16x16x32, B-operand, 8 n-tiles x 4 k-tiles):
// chunk = ((n>>4)*4 + (k>>5))*64 + ((k>>3)&3)*16 + (n&15); flat = chunk*8 + (k&7)
__device__ __forceinline__ int fragidx(int k, int n) {
  return ((((n >> 4) * 4 + (k >> 5)) * 64 + ((k >> 3) & 3) * 16 + (n & 15)) << 3) + (k & 7);
}

// ---- prep: WhF/WlF = split-bf16(Wk @ Wa1) in FRAGMENT order; c3 = rel@Wa3 + b_att
__global__ __launch_bounds__(256) void prep_kernel(
    const float* __restrict__ Wk, const float* __restrict__ Watt,
    const float* __restrict__ batt, const float* __restrict__ rel,
    unsigned short* __restrict__ WhF, unsigned short* __restrict__ WlF,
    float* __restrict__ c3) {
  __shared__ float rowS[D];
  __shared__ float psum[2][D];
  const int blk = blockIdx.x;      // 0..(D+BB-1): row k of Wkk, then batch rows
  const int t = threadIdx.x;       // 256
  const float* src = (blk < D) ? (Wk + blk * D) : (rel + (blk - D) * D);
  const float* W   = (blk < D) ? Watt : (Watt + 2 * D * D);
  if (t < D) rowS[t] = src[t];
  __syncthreads();
  const int d = t & 127, half = t >> 7;
  const float* Wp = W + (half * 64) * D + d;
  float a = 0.f;
  #pragma unroll 8
  for (int k = 0; k < 64; ++k) a += rowS[half * 64 + k] * Wp[k * D];
  psum[half][d] = a;
  __syncthreads();
  if (t < D) {
    const float w = psum[0][t] + psum[1][t];
    if (blk < D) {
      const unsigned int ub = fbits(w);
      const int idx = fragidx(blk, t);        // k = blk, n = t
      WhF[idx] = (unsigned short)(ub >> 16);
      WlF[idx] = f2bf(w - ubits(ub & 0xFFFF0000u));
    } else {
      c3[(blk - D) * D + t] = w + batt[t];
    }
  }
}

// ---- g1 = (key*mask) @ Wkk via split-bf16 MFMA (fp32-accurate), stored fp16 ----
// Weights arrive pre-swizzled: staging is a straight linear copy, conflict-free.
// Persistent blocks: grid 1024, 4 tiles each; weight re-reads hit L2.
__global__ __launch_bounds__(256) void gemm_g1_kernel(
    const float* __restrict__ key, const int* __restrict__ mask,
    const unsigned short* __restrict__ WhF, const unsigned short* __restrict__ WlF,
    unsigned short* __restrict__ g1h) {
  __shared__ __align__(16) unsigned short whlds[16384];
  __shared__ __align__(16) unsigned short wllds[16384];
  const int t = threadIdx.x;
  #pragma unroll
  for (int i = 0; i < 8; ++i) {
    const int unit = t + i * 256;            // 16B units 0..2047
    *reinterpret_cast<uint4*>(&whlds[unit * 8]) = *reinterpret_cast<const uint4*>(WhF + unit * 8);
    *reinterpret_cast<uint4*>(&wllds[unit * 8]) = *reinterpret_cast<const uint4*>(WlF + unit * 8);
  }
  __syncthreads();
  const int wave = t >> 6, lane = t & 63;
  const int q = lane >> 4, l15 = lane & 15;
  const int ntiles = (BB * NN) / 64;         // 4096
  for (int tile = blockIdx.x; tile < ntiles; tile += gridDim.x) {
    const long rowbase = (long)tile * 64 + wave * 16;
    const long r = rowbase + l15;
    const int mk = mask[r];
    short8 ah[4], al[4];
    #pragma unroll
    for (int kt = 0; kt < 4; ++kt) {
      const float* kp = key + r * D + kt * 32 + q * 8;
      float xs[8];
      *reinterpret_cast<float4*>(&xs[0]) = *reinterpret_cast<const float4*>(kp);
      *reinterpret_cast<float4*>(&xs[4]) = *reinterpret_cast<const float4*>(kp + 4);
      union { unsigned int u[4]; short8 v; } cvh, cvl;
      #pragma unroll
      for (int p2 = 0; p2 < 4; ++p2) {
        float a = xs[2 * p2], b = xs[2 * p2 + 1];
        if (!mk) { a = 0.f; b = 0.f; }
        const unsigned int ua = fbits(a), ub = fbits(b);
        cvh.u[p2] = (ua >> 16) | (ub & 0xFFFF0000u);
        const float ra = a - ubits(ua & 0xFFFF0000u);
        const float rb = b - ubits(ub & 0xFFFF0000u);
        cvl.u[p2] = (unsigned int)f2bf(ra) | ((unsigned int)f2bf(rb) << 16);
      }
      ah[kt] = cvh.v; al[kt] = cvl.v;
    }
    f32x4 acc[8];
    #pragma unroll
    for (int c = 0; c < 8; ++c) acc[c] = (f32x4){0.f, 0.f, 0.f, 0.f};
    #pragma unroll
    for (int kt = 0; kt < 4; ++kt) {
      #pragma unroll
      for (int c = 0; c < 8; ++c) {
        const short8 bh = *reinterpret_cast<const short8*>(&whlds[((c * 4 + kt) * 64 + lane) * 8]);
        const short8 bl = *reinterpret_cast<const short8*>(&wllds[((c * 4 + kt) * 64 + lane) * 8]);
        acc[c] = __builtin_amdgcn_mfma_f32_16x16x32_bf16(ah[kt], bh, acc[c], 0, 0, 0);
        acc[c] = __builtin_amdgcn_mfma_f32_16x16x32_bf16(al[kt], bh, acc[c], 0, 0, 0);
        acc[c] = __builtin_amdgcn_mfma_f32_16x16x32_bf16(ah[kt], bl, acc[c], 0, 0, 0);
      }
    }
    // C/D layout: col(n) = c*16 + (lane&15), row(m) = rowbase + (lane>>4)*4 + reg
    #pragma unroll
    for (int c = 0; c < 8; ++c) {
      #pragma unroll
      for (int reg = 0; reg < 4; ++reg) {
        const long row = rowbase + q * 4 + reg;
        g1h[row * D + c * 16 + l15] = f2h(acc[c][reg]);
      }
    }
  }
}

// ---- fused 3-hop kernel: one block (512 thr) per batch row ---------------------
template <int USEVH>
__global__ __launch_bounds__(512, 4) void hops_kernel(
    const float* __restrict__ e1, const int* __restrict__ mask,
    const float* __restrict__ value, const unsigned short* __restrict__ g1h,
    unsigned short* __restrict__ vh,
    const float* __restrict__ Wlin, const float* __restrict__ blin,
    const float* __restrict__ Watt, const float* __restrict__ Wv,
    const float* __restrict__ c3, float* __restrict__ out) {
  __shared__ float uS[D], cS[D], ubS[D], opS[D];
  __shared__ float attS[NN];
  __shared__ float part[4][D];
  __shared__ float oscr[8][D];
  __shared__ float redA[8], redB[8];
  const int b = blockIdx.x;
  const int t = threadIdx.x;
  const int wv = t >> 6, lane = t & 63;
  const long base = (long)b * NN * D;
  const int* mb = mask + b * NN;
  if (t < D) uS[t] = e1[b * D + t];
  __syncthreads();
  for (int hop = 0; hop < 3; ++hop) {
    // phase 1: 4 roles x 128 threads: role0/1 = c halves, role2/3 = ub halves
    {
      const int d = t & 127, role = t >> 7;
      const float* W = (role < 2) ? (Watt + D * D) : Wlin;
      const int k0 = (role & 1) * 64;
      const float* Wp = W + k0 * D + d;
      float a = 0.f;
      #pragma unroll 8
      for (int k = 0; k < 64; ++k) a += uS[k0 + k] * Wp[k * D];
      part[role][d] = a;
    }
    __syncthreads();
    if (t < D) cS[t] = part[0][t] + part[1][t] + c3[b * D + t];
    else if (t < 2 * D) { const int d = t - D; ubS[d] = lrelu(part[2][d] + part[3][d] + blin[d]); }
    __syncthreads();
    // phase 2: att[n] = sum_d lrelu(g1[n,d] + c[d]); 32 groups x 16 lanes, 16 iters
    {
      const int grp = t >> 4, l = t & 15, d0 = l * 8;
      float creg[8];
      #pragma unroll
      for (int j = 0; j < 8; ++j) creg[j] = cS[d0 + j];
      #pragma unroll 4
      for (int i = 0; i < 16; ++i) {
        const int n = i * 32 + grp;
        const uint4 raw = *reinterpret_cast<const uint4*>(g1h + base + (long)n * D + d0);
        const unsigned short* e = reinterpret_cast<const unsigned short*>(&raw);
        float s = 0.f;
        #pragma unroll
        for (int j = 0; j < 8; ++j) s += lrelu(h2f(e[j]) + creg[j]);
        #pragma unroll
        for (int off = 8; off > 0; off >>= 1) s += __shfl_xor(s, off, 16);
        if (l == 0) attS[n] = s;
      }
    }
    __syncthreads();
    // phase 3: masked softmax (max over ALL n incl. masked — matches ref); n = t
    {
      const float av = attS[t];
      float m = av;
      #pragma unroll
      for (int off = 32; off > 0; off >>= 1) m = fmaxf(m, __shfl_xor(m, off, 64));
      if (lane == 0) redA[wv] = m;
      __syncthreads();
      m = redA[0];
      #pragma unroll
      for (int w2 = 1; w2 < 8; ++w2) m = fmaxf(m, redA[w2]);
      const float e0 = __expf(av - m) * (mb[t] ? 1.f : 0.f);
      float ss = e0;
      #pragma unroll
      for (int off = 32; off > 0; off >>= 1) ss += __shfl_xor(ss, off, 64);
      if (lane == 0) redB[wv] = ss;
      __syncthreads();
      float s = 1e-5f;
      #pragma unroll
      for (int w2 = 0; w2 < 8; ++w2) s += redB[w2];
      attS[t] = e0 / s;
    }
    __syncthreads();
    // phase 4: o_pre[d] = sum_n p[n] * value[n,d]; hop0 converts value -> fp16 ws
    {
      const int grp = t >> 4, l = t & 15, d0 = l * 8;
      float acc8[8];
      #pragma unroll
      for (int j = 0; j < 8; ++j) acc8[j] = 0.f;
      if (USEVH && hop == 0) {
        #pragma unroll 2
        for (int i = 0; i < 16; ++i) {
          const int n = i * 32 + grp;
          const float p = attS[n];
          float vv[8];
          *reinterpret_cast<float4*>(&vv[0]) = *reinterpret_cast<const float4*>(value + base + (long)n * D + d0);
          *reinterpret_cast<float4*>(&vv[4]) = *reinterpret_cast<const float4*>(value + base + (long)n * D + d0 + 4);
          unsigned short hv[8];
          #pragma unroll
          for (int j = 0; j < 8; ++j) { hv[j] = f2h(vv[j]); acc8[j] += p * vv[j]; }
          *reinterpret_cast<uint4*>(vh + base + (long)n * D + d0) = *reinterpret_cast<const uint4*>(hv);
        }
      } else if (USEVH) {
        #pragma unroll 4
        for (int i = 0; i < 16; ++i) {
          const int n = i * 32 + grp;
          const float p = attS[n];
          const uint4 raw = *reinterpret_cast<const uint4*>(vh + base + (long)n * D + d0);
          const unsigned short* e = reinterpret_cast<const unsigned short*>(&raw);
          #pragma unroll
          for (int j = 0; j < 8; ++j) acc8[j] += p * h2f(e[j]);
        }
      } else {
        #pragma unroll 2
        for (int i = 0; i < 16; ++i) {
          const int n = i * 32 + grp;
          const float p = attS[n];
          float vv[8];
          *reinterpret_cast<float4*>(&vv[0]) = *reinterpret_cast<const float4*>(value + base + (long)n * D + d0);
          *reinterpret_cast<float4*>(&vv[4]) = *reinterpret_cast<const float4*>(value + base + (long)n * D + d0 + 4);
          #pragma unroll
          for (int j = 0; j < 8; ++j) acc8[j] += p * vv[j];
        }
      }
      #pragma unroll
      for (int j = 0; j < 8; ++j) {
        acc8[j] += __shfl_xor(acc8[j], 16, 64);
        acc8[j] += __shfl_xor(acc8[j], 32, 64);
      }
      if (lane < 16) {
        #pragma unroll
        for (int j = 0; j < 8; ++j) oscr[wv][lane * 8 + j] = acc8[j];
      }
    }
    __syncthreads();
    if (t < D) {
      float s = 0.f;
      #pragma unroll
      for (int w2 = 0; w2 < 8; ++w2) s += oscr[w2][t];
      opS[t] = s;
    }
    __syncthreads();
    // phase 5a: o = o_pre @ Wv, 4-way k-split
    {
      const int d = t & 127, role = t >> 7;
      const int k0 = role * 32;
      const float* Wp = Wv + k0 * D + d;
      float a = 0.f;
      #pragma unroll 8
      for (int k = 0; k < 32; ++k) a += opS[k0 + k] * Wp[k * D];
      part[role][d] = a;
    }
    __syncthreads();
    // phase 5b: u = l2norm(ub + o)
    {
      float un = 0.f, sq = 0.f;
      if (t < D) {
        un = ubS[t] + part[0][t] + part[1][t] + part[2][t] + part[3][t];
        sq = un * un;
      }
      #pragma unroll
      for (int off = 32; off > 0; off >>= 1) sq += __shfl_xor(sq, off, 64);
      if (lane == 0) redA[wv] = sq;
      __syncthreads();
      float ns = 0.f;
      #pragma unroll
      for (int w2 = 0; w2 < 8; ++w2) ns += redA[w2];
      const float norm = sqrtf(ns);
      const float inv = (norm > 1e-12f) ? (1.f / norm) : 1e12f;
      if (t < D) uS[t] = un * inv;
    }
    __syncthreads();
  }
  if (t < D) out[b * D + t] = uS[t];
}

extern "C" void kernel_launch(void* const* d_in, const int* in_sizes, int n_in,
                              void* d_out, int out_size, void* d_ws, size_t ws_size,
                              hipStream_t stream) {
  const float* e1   = (const float*)d_in[0];
  const float* rel  = (const float*)d_in[1];
  const float* key  = (const float*)d_in[2];
  const float* val  = (const float*)d_in[3];
  const int*   mask = (const int*)d_in[4];
  const float* Wk   = (const float*)d_in[5];
  const float* Wv   = (const float*)d_in[6];
  const float* Wlin = (const float*)d_in[7];
  const float* blin = (const float*)d_in[8];
  const float* Watt = (const float*)d_in[9];
  const float* batt = (const float*)d_in[10];
  float* out = (float*)d_out;

  char* ws = (char*)d_ws;
  unsigned short* WhF = (unsigned short*)ws;                   // 32 KB (fragment order)
  unsigned short* WlF = (unsigned short*)(ws + 32 * 1024);     // 32 KB (fragment order)
  float*          c3  = (float*)(ws + 64 * 1024);              // 256 KB
  unsigned short* g1h = (unsigned short*)(ws + 512 * 1024);    // 64 MiB fp16
  const size_t g1bytes = (size_t)BB * NN * D * sizeof(unsigned short);
  unsigned short* vh  = (unsigned short*)(ws + 512 * 1024 + g1bytes);  // 64 MiB fp16

  const size_t need_vh = 512 * 1024 + 2 * g1bytes;
  const bool usevh = (ws_size >= need_vh);

  prep_kernel<<<D + BB, 256, 0, stream>>>(Wk, Watt, batt, rel, WhF, WlF, c3);
  gemm_g1_kernel<<<1024, 256, 0, stream>>>(key, mask, WhF, WlF, g1h);
  if (usevh) {
    hops_kernel<1><<<BB, 512, 0, stream>>>(e1, mask, val, g1h, vh, Wlin, blin, Watt, Wv, c3, out);
  } else {
    hops_kernel<0><<<BB, 512, 0, stream>>>(e1, mask, val, g1h, vh, Wlin, blin, Watt, Wv, c3, out);
  }
}